// Round 5
// baseline (282.636 us; speedup 1.0000x reference)
//
#include <hip/hip_runtime.h>
#include <hip/hip_fp16.h>
#include <math.h>

// Problem constants
#define NB 392      // n = b*oh*ow = 2*14*14
#define NI 288      // K*K*B = 9*32
#define NC 32       // C
#define NQ 16       // PSIZE
#define CQ 512      // NC*NQ
#define CH 544      // B*(PSIZE+1)
#define EPSV 1e-6f
#define NPAD 400    // n padded to 25 MFMA row-tiles

// element counts
#define P16E (NI*NPAD*32)     // p16[i][n][32k]  fp16, k>=16 zero-pad
#define W16E (NI*CQ*32)       // w16[i][cq][32k] fp16, k>=16 zero-pad
#define AFACE (NB*NI)         // afac floats
#define VJ0E (NPAD*CQ)        // vj0 floats

// ws float offsets
#define OFF_AFAC 0
#define OFF_P16  (AFACE)
#define OFF_W16  (OFF_P16 + P16E/2)
#define OFF_VJ0  (OFF_W16 + W16E/2)
#define OFF_VOT  (OFF_VJ0 + VJ0E)

// out layout (floats)
#define OFF_AOUT 200704       // NB*CQ
#define OFF_CAT  213248       // OFF_AOUT + NB*NC

typedef _Float16 v8h __attribute__((ext_vector_type(8)));
typedef float v4f __attribute__((ext_vector_type(4)));

// ---------------------------------------------------------------------------
// Gather from x via the unfold channel-major reinterpret.
__device__ __forceinline__ float gather_x(const float* __restrict__ x, int n, int j) {
    int c_idx = j / 9;
    int rem = j - c_idx * 9;
    int ki = rem / 3;
    int kj = rem - ki * 3;
    int b_ = n / 196;
    int rest = n - b_ * 196;
    int yy = rest / 14;
    int xx = rest - yy * 14;
    int iy = yy + ki - 1;
    int ix = xx + kj - 1;
    float v = 0.f;
    if ((unsigned)iy < 14u && (unsigned)ix < 14u)
        v = x[((b_ * 14 + iy) * 14 + ix) * CH + c_idx];
    return v;
}

// p16 (fp16, padded) + afac (fp32): grid-stride elementwise.
__global__ __launch_bounds__(256) void prep_pa(const float* __restrict__ x,
                                               ushort* __restrict__ p16,
                                               float* __restrict__ afac) {
    int tid = blockIdx.x * 256 + threadIdx.x;
    if (tid < P16E) {
        int k = tid & 31;
        int i = tid / (NPAD * 32);
        int n = (tid >> 5) - i * NPAD;
        float v = 0.f;
        if (n < NB && k < 16) {
            int j = (i >> 5) * CH + (i & 31) * 16 + k;
            v = gather_x(x, n, j);
        }
        p16[tid] = __half_as_ushort(__float2half(v));
    } else if (tid < P16E + AFACE) {
        int t3 = tid - P16E;
        int i = t3 % NI;
        int n = t3 / NI;
        int j = (i >> 5) * CH + 512 + (i & 31);
        float v = gather_x(x, n, j);
        float a = fminf(fmaxf(v, 1e-4f), 1.0f);
        afac[t3] = a / (a + EPSV);
    }
}

// w16[i][cq][32k] = wts[i][cq>>4][k][cq&15] (k<16), via LDS transpose.
// Block per i: coalesced float4 reads, coalesced uint (half2) writes.
__global__ __launch_bounds__(256) void prep_w(const float* __restrict__ wts,
                                              ushort* __restrict__ w16) {
    __shared__ float wl[8192];   // 32 KB: wts[i] tile, [c][p][q] flat
    int i = blockIdx.x;
    int t = threadIdx.x;
    const float4* src = (const float4*)(wts + (size_t)i * 8192);
#pragma unroll
    for (int it = 0; it < 8; ++it)
        *(float4*)&wl[(it * 256 + t) * 4] = src[it * 256 + t];
    __syncthreads();
    uint* dst = (uint*)(w16 + (size_t)i * 16384);
    for (int it = 0; it < 32; ++it) {
        int idx = it * 256 + t;          // uint index = cq*16 + kpair
        int kpair = idx & 15;
        int cq = idx >> 4;
        uint val = 0;
        if (kpair < 8) {
            int base = (cq >> 4) * 256 + (cq & 15);
            __half2 h = __floats2half2_rn(wl[base + (2 * kpair) * 16],
                                          wl[base + (2 * kpair + 1) * 16]);
            val = *(uint*)&h;
        }
        dst[idx] = val;
    }
}

// ---------------------------------------------------------------------------
// votes via MFMA, full-tile staging. Block (mt, i), 1 wave.
// All 32 ct-tiles accumulate into a padded LDS tile [16][520] (pad 16 B ->
// writes are 2-way-at-worst = free), then 16 stores of exactly 1 KB each
// (64 lanes x dwordx4) -> no partial-sector write amplification.
__global__ __launch_bounds__(64) void votes_k(const ushort* __restrict__ p16,
                                              const ushort* __restrict__ w16,
                                              ushort* __restrict__ votes) {
    __shared__ ushort tile[16 * 520];   // 16.25 KB
    int mt = blockIdx.x;          // 0..24
    int i = blockIdx.y;           // 0..287
    int l = threadIdx.x;
    int col = l & 15;
    int quad = l >> 4;

    const v8h* ap = (const v8h*)(p16 + ((size_t)(i * NPAD + mt * 16 + col) << 5) + (quad << 3));
    v8h av = *ap;

#pragma clang loop unroll_count(4)
    for (int ct = 0; ct < 32; ++ct) {
        const v8h* bp = (const v8h*)(w16 + ((size_t)(i * CQ + ct * 16 + col) << 5) + (quad << 3));
        v8h bv = *bp;
        v4f acc = {0.f, 0.f, 0.f, 0.f};
        acc = __builtin_amdgcn_mfma_f32_16x16x32_f16(av, bv, acc, 0, 0, 0);
#pragma unroll
        for (int r = 0; r < 4; ++r)
            tile[(quad * 4 + r) * 520 + ct * 16 + col] = __half_as_ushort(__float2half(acc[r]));
    }
    __syncthreads();
#pragma unroll 4
    for (int row = 0; row < 16; ++row) {
        int n_out = mt * 16 + row;
        if (n_out >= NB) break;
        uint4 d = *(const uint4*)&tile[row * 520 + l * 8];
        *(uint4*)(votes + (((size_t)n_out * NI + i) << 9) + l * 8) = d;
    }
}

// ---------------------------------------------------------------------------
// s0 GEMM: iter-0 routing weights are afs/32 (vote-independent), so
// s0[n,cq] = sum_{i,p} (afs[n,i]/32 * p[n,i,p]) * W[i,p,cq]  -- one GEMM,
// K = 4608. Block (mt, ct=c), 1 wave, K-loop over i with A-frag scaled by
// afs/32 in fp16. Squash fused in-wave (q-sum via 4 shfls); writes vj0 fp32.
__global__ __launch_bounds__(64) void s0_k(const ushort* __restrict__ p16,
                                           const ushort* __restrict__ w16,
                                           const float* __restrict__ afac,
                                           float* __restrict__ vj0) {
    int mt = blockIdx.x;   // 0..24
    int ct = blockIdx.y;   // 0..31 (== c)
    int l = threadIdx.x;
    int col = l & 15;
    int quad = l >> 4;
    int n_row = mt * 16 + col;
    v4f acc = {0.f, 0.f, 0.f, 0.f};

#pragma clang loop unroll_count(2)
    for (int i = 0; i < NI; ++i) {
        v8h av = *(const v8h*)(p16 + ((size_t)(i * NPAD + n_row) << 5) + (quad << 3));
        float sc = (n_row < NB ? afac[n_row * NI + i] : 0.f) * (1.0f / 32.0f);
        v8h avs = av * (_Float16)sc;
        v8h bv = *(const v8h*)(w16 + ((size_t)(i * CQ + ct * 16 + col) << 5) + (quad << 3));
        acc = __builtin_amdgcn_mfma_f32_16x16x32_f16(avs, bv, acc, 0, 0, 0);
    }
    // squash per n-row: s2 = sum over the 16 q (= col lanes within the quad)
#pragma unroll
    for (int r = 0; r < 4; ++r) {
        float x = acc[r] * acc[r];
        x += __shfl_xor(x, 1);
        x += __shfl_xor(x, 2);
        x += __shfl_xor(x, 4);
        x += __shfl_xor(x, 8);
        float f = (x / (1.f + x)) / sqrtf(x + EPSV);
        int n_o = mt * 16 + quad * 4 + r;
        if (n_o < NB)
            vj0[n_o * CQ + ct * 16 + col] = f * acc[r];
    }
}

// ---------------------------------------------------------------------------
// Fused dynamic routing, 2 vote passes (iter0 precomputed as vj0).
// Block = n, 512 threads (8 waves). Lane: c = l&31, g = l>>5; wave wv step s
// handles i = (s*8+wv)*2+g. b_ij is linear in history -> only cumulative vjr.
__global__ __launch_bounds__(512) void routing_k(const ushort* __restrict__ votes,
                                                 const float* __restrict__ afac,
                                                 const float* __restrict__ vj0,
                                                 float* __restrict__ out) {
    __shared__ float afs[NI];
    __shared__ float sred[8 * CQ];    // 16 KB
    __shared__ float vj[CQ];
    __shared__ float aout_s[NC];

    int n = blockIdx.x;
    int t = threadIdx.x;
    int wv = t >> 6;
    int l = t & 63;
    int c = l & 31;
    int g = l >> 5;

    for (int idx = t; idx < NI; idx += 512) afs[idx] = afac[n * NI + idx];
    __syncthreads();

    const ushort* vb = votes + (size_t)n * NI * CQ;
    float vjr[16];    // cumulative sum of vj over past iters (starts at vj0)
    float sreg[16];
    {
        const float4* v0p = (const float4*)(vj0 + (size_t)n * CQ + (c << 4));
#pragma unroll
        for (int q4 = 0; q4 < 4; ++q4) {
            float4 f = v0p[q4];
            vjr[q4 * 4] = f.x; vjr[q4 * 4 + 1] = f.y;
            vjr[q4 * 4 + 2] = f.z; vjr[q4 * 4 + 3] = f.w;
        }
    }

    for (int iter = 1; iter <= 2; ++iter) {
#pragma unroll
        for (int q = 0; q < 16; ++q) sreg[q] = 0.f;

        // depth-2 prefetch
        const uint4* r0 = (const uint4*)(vb + ((size_t)((0 * 8 + wv) * 2 + g) << 9) + (c << 4));
        uint4 a0 = r0[0], a1 = r0[1];
        const uint4* r1 = (const uint4*)(vb + ((size_t)((1 * 8 + wv) * 2 + g) << 9) + (c << 4));
        uint4 b0 = r1[0], b1 = r1[1];

#pragma clang loop unroll_count(2)
        for (int s = 0; s < 18; ++s) {
            int i = ((s << 3) + wv) * 2 + g;
            uint4 c0 = a0, c1 = a1;
            a0 = b0; a1 = b1;
            if (s + 2 < 18) {
                const uint4* rn = (const uint4*)(vb + ((size_t)((((s + 2) << 3) + wv) * 2 + g) << 9) + (c << 4));
                b0 = rn[0]; b1 = rn[1];
            }
            float vt[16];
            {
                float2 f;
                f = __half22float2(*(const __half2*)&c0.x); vt[0] = f.x;  vt[1] = f.y;
                f = __half22float2(*(const __half2*)&c0.y); vt[2] = f.x;  vt[3] = f.y;
                f = __half22float2(*(const __half2*)&c0.z); vt[4] = f.x;  vt[5] = f.y;
                f = __half22float2(*(const __half2*)&c0.w); vt[6] = f.x;  vt[7] = f.y;
                f = __half22float2(*(const __half2*)&c1.x); vt[8] = f.x;  vt[9] = f.y;
                f = __half22float2(*(const __half2*)&c1.y); vt[10] = f.x; vt[11] = f.y;
                f = __half22float2(*(const __half2*)&c1.z); vt[12] = f.x; vt[13] = f.y;
                f = __half22float2(*(const __half2*)&c1.w); vt[14] = f.x; vt[15] = f.y;
            }
            float ah = 0.f;
#pragma unroll
            for (int q = 0; q < 16; ++q) ah += vt[q] * vjr[q];
            float e = __expf(ah);   // |b| <= ~0.7: no max-sub needed
            float ssum = e;
            ssum += __shfl_xor(ssum, 1);
            ssum += __shfl_xor(ssum, 2);
            ssum += __shfl_xor(ssum, 4);
            ssum += __shfl_xor(ssum, 8);
            ssum += __shfl_xor(ssum, 16);
            float cij = e * __builtin_amdgcn_rcpf(ssum) * afs[i];
#pragma unroll
            for (int q = 0; q < 16; ++q) sreg[q] += cij * vt[q];
        }

        // fold g-halves, write 8 per-wave partials, tree-reduce
#pragma unroll
        for (int q = 0; q < 16; ++q) sreg[q] += __shfl_xor(sreg[q], 32);
        if (g == 0) {
            float* sw = &sred[wv * CQ + (c << 4)];
#pragma unroll
            for (int q4 = 0; q4 < 4; ++q4)
                *(float4*)(sw + q4 * 4) = make_float4(sreg[q4 * 4], sreg[q4 * 4 + 1],
                                                      sreg[q4 * 4 + 2], sreg[q4 * 4 + 3]);
        }
        __syncthreads();
        {
            float ssum = 0.f;
#pragma unroll
            for (int k = 0; k < 8; ++k) ssum += sred[k * CQ + t];
            sred[t] = ssum;
        }
        __syncthreads();

        // squash (threads 0..31, one c each)
        if (t < NC) {
            float s2 = 0.f;
#pragma unroll
            for (int q = 0; q < 16; ++q) {
                float s = sred[t * 16 + q];
                s2 += s * s;
            }
            float f = (s2 / (1.f + s2)) / sqrtf(s2 + EPSV);
            float vn2 = 0.f;
#pragma unroll
            for (int q = 0; q < 16; ++q) {
                float v = f * sred[t * 16 + q];
                vj[t * 16 + q] = v;
                vn2 += v * v;
            }
            if (iter == 2) {
                float ao = sqrtf(vn2 + EPSV);
                ao = fminf(fmaxf(ao, 1e-4f), 1.f - 1e-4f);
                aout_s[t] = ao;
            }
        }
        __syncthreads();
        if (iter == 1) {
            const float4* vp4 = (const float4*)(&vj[c << 4]);
#pragma unroll
            for (int q4 = 0; q4 < 4; ++q4) {
                float4 f = vp4[q4];
                vjr[q4 * 4] += f.x; vjr[q4 * 4 + 1] += f.y;
                vjr[q4 * 4 + 2] += f.z; vjr[q4 * 4 + 3] += f.w;
            }
        }
    }

    // outputs: p_out, a_out, concat(out)
    {
        float v = vj[t];   // 512 threads == CQ
        out[(size_t)n * CQ + t] = v;
        out[OFF_CAT + (size_t)n * 544 + t] = v;
    }
    if (t < NC) {
        float ao = aout_s[t];
        out[OFF_AOUT + n * 32 + t] = ao;
        out[OFF_CAT + (size_t)n * 544 + 512 + t] = ao;
    }
}

// ---------------------------------------------------------------------------
extern "C" void kernel_launch(void* const* d_in, const int* in_sizes, int n_in,
                              void* d_out, int out_size, void* d_ws, size_t ws_size,
                              hipStream_t stream) {
    const float* x = (const float*)d_in[0];
    const float* wts = (const float*)d_in[1];
    float* out = (float*)d_out;
    float* ws = (float*)d_ws;

    float* afac = ws + OFF_AFAC;
    ushort* p16 = (ushort*)(ws + OFF_P16);
    ushort* w16 = (ushort*)(ws + OFF_W16);
    float* vj0 = ws + OFF_VJ0;
    ushort* votes = (ushort*)(ws + OFF_VOT);

    hipLaunchKernelGGL(prep_w, dim3(NI), dim3(256), 0, stream, wts, w16);
    hipLaunchKernelGGL(prep_pa, dim3((P16E + AFACE + 255) / 256), dim3(256), 0, stream,
                       x, p16, afac);
    hipLaunchKernelGGL(votes_k, dim3(25, NI), dim3(64), 0, stream,
                       p16, w16, votes);
    hipLaunchKernelGGL(s0_k, dim3(25, 32), dim3(64), 0, stream,
                       p16, w16, afac, vj0);
    hipLaunchKernelGGL(routing_k, dim3(NB), dim3(512), 0, stream,
                       votes, afac, vj0, out);
}

// Round 6
// 159.546 us; speedup vs baseline: 1.7715x; 1.7715x over previous
//
#include <hip/hip_runtime.h>
#include <hip/hip_fp16.h>
#include <math.h>

// Problem constants
#define NB 392      // n = b*oh*ow = 2*14*14
#define NI 288      // K*K*B = 9*32
#define NC 32       // C
#define NQ 16       // PSIZE
#define CQ 512      // NC*NQ
#define CH 544      // B*(PSIZE+1)
#define EPSV 1e-6f
#define NPAD 448    // n padded to 7 tiles of 64 rows

// element counts
#define P16E (NI*NPAD*32)     // p16[i][n][32k]  fp16, k>=16 zero-pad
#define W16E (NI*CQ*32)       // w16[i][cq][32k] fp16, k>=16 zero-pad
#define AFACE (NB*NI)         // afac floats

// ws float offsets
#define OFF_AFAC 0
#define OFF_P16  (AFACE)
#define OFF_W16  (OFF_P16 + P16E/2)
#define OFF_VOT  (OFF_W16 + W16E/2)

// out layout (floats)
#define OFF_AOUT 200704       // NB*CQ
#define OFF_CAT  213248       // OFF_AOUT + NB*NC

typedef _Float16 v8h __attribute__((ext_vector_type(8)));
typedef float v4f __attribute__((ext_vector_type(4)));

// ---------------------------------------------------------------------------
// Gather from x via the unfold channel-major reinterpret.
__device__ __forceinline__ float gather_x(const float* __restrict__ x, int n, int j) {
    int c_idx = j / 9;
    int rem = j - c_idx * 9;
    int ki = rem / 3;
    int kj = rem - ki * 3;
    int b_ = n / 196;
    int rest = n - b_ * 196;
    int yy = rest / 14;
    int xx = rest - yy * 14;
    int iy = yy + ki - 1;
    int ix = xx + kj - 1;
    float v = 0.f;
    if ((unsigned)iy < 14u && (unsigned)ix < 14u)
        v = x[((b_ * 14 + iy) * 14 + ix) * CH + c_idx];
    return v;
}

// p16 (fp16, padded) + afac (fp32): grid-stride elementwise.
__global__ __launch_bounds__(256) void prep_pa(const float* __restrict__ x,
                                               ushort* __restrict__ p16,
                                               float* __restrict__ afac) {
    int tid = blockIdx.x * 256 + threadIdx.x;
    if (tid < P16E) {
        int k = tid & 31;
        int i = tid / (NPAD * 32);
        int n = (tid >> 5) - i * NPAD;
        float v = 0.f;
        if (n < NB && k < 16) {
            int j = (i >> 5) * CH + (i & 31) * 16 + k;
            v = gather_x(x, n, j);
        }
        p16[tid] = __half_as_ushort(__float2half(v));
    } else if (tid < P16E + AFACE) {
        int t3 = tid - P16E;
        int i = t3 % NI;
        int n = t3 / NI;
        int j = (i >> 5) * CH + 512 + (i & 31);
        float v = gather_x(x, n, j);
        float a = fminf(fmaxf(v, 1e-4f), 1.0f);
        afac[t3] = a / (a + EPSV);
    }
}

// w16[i][cq][32k] = wts[i][cq>>4][k][cq&15] (k<16), via LDS transpose.
// Block per i: coalesced float4 reads, coalesced uint (half2) writes.
__global__ __launch_bounds__(256) void prep_w(const float* __restrict__ wts,
                                              ushort* __restrict__ w16) {
    __shared__ float wl[8192];   // 32 KB: wts[i] tile, [c][p][q] flat
    int i = blockIdx.x;
    int t = threadIdx.x;
    const float4* src = (const float4*)(wts + (size_t)i * 8192);
#pragma unroll
    for (int it = 0; it < 8; ++it)
        *(float4*)&wl[(it * 256 + t) * 4] = src[it * 256 + t];
    __syncthreads();
    uint* dst = (uint*)(w16 + (size_t)i * 16384);
    for (int it = 0; it < 32; ++it) {
        int idx = it * 256 + t;          // uint index = cq*16 + kpair
        int kpair = idx & 15;
        int cq = idx >> 4;
        uint val = 0;
        if (kpair < 8) {
            int base = (cq >> 4) * 256 + (cq & 15);
            __half2 h = __floats2half2_rn(wl[base + (2 * kpair) * 16],
                                          wl[base + (2 * kpair + 1) * 16]);
            val = *(uint*)&h;
        }
        dst[idx] = val;
    }
}

// ---------------------------------------------------------------------------
// votes via MFMA, M=64 blocking. Block (mtt 0..6, i), 256 threads = 4 waves;
// wave wv owns rows [mtt*64 + wv*16, +16). Each wave re-loads the shared
// B-frag (L1-served; 4x less w16 L2/L3 traffic than 1-wave M=16 blocks).
// Accumulate all 32 ct-tiles into padded LDS [64][520] (row pitch 1040 B =
// 16B-aligned), then store 64 rows of exactly 1 KB -> no write amplification.
__global__ __launch_bounds__(256) void votes_k(const ushort* __restrict__ p16,
                                               const ushort* __restrict__ w16,
                                               ushort* __restrict__ votes) {
    __shared__ ushort tile[64 * 520];   // 65 KB
    int mtt = blockIdx.x;         // 0..6
    int i = blockIdx.y;           // 0..287
    int t = threadIdx.x;
    int wv = t >> 6;
    int l = t & 63;
    int col = l & 15;
    int quad = l >> 4;

    int row_a = mtt * 64 + wv * 16 + col;
    v8h av = *(const v8h*)(p16 + ((size_t)(i * NPAD + row_a) << 5) + (quad << 3));
    ushort* tl = tile + (wv * 16) * 520;

#pragma clang loop unroll_count(4)
    for (int ct = 0; ct < 32; ++ct) {
        v8h bv = *(const v8h*)(w16 + ((size_t)(i * CQ + ct * 16 + col) << 5) + (quad << 3));
        v4f acc = {0.f, 0.f, 0.f, 0.f};
        acc = __builtin_amdgcn_mfma_f32_16x16x32_f16(av, bv, acc, 0, 0, 0);
#pragma unroll
        for (int r = 0; r < 4; ++r)
            tl[(quad * 4 + r) * 520 + ct * 16 + col] = __half_as_ushort(__float2half(acc[r]));
    }
    __syncthreads();
    // store 64 rows x 1 KB; each wave handles one row per k-step (linear
    // 16B-stride LDS reads, fully coalesced 1KB global stores)
#pragma unroll 4
    for (int k = 0; k < 16; ++k) {
        int idx = k * 256 + t;       // 0..4095
        int row = idx >> 6;
        int off = idx & 63;          // uint4 index within row
        int n_out = mtt * 64 + row;
        if (n_out < NB) {
            uint4 d = *(const uint4*)&tile[row * 520 + off * 8];
            *(uint4*)(votes + (((size_t)n_out * NI + i) << 9) + off * 8) = d;
        }
    }
}

// ---------------------------------------------------------------------------
// Fused dynamic routing, 3 passes. Block = n, 512 threads (8 waves).
// Lane: c = l&31, g = l>>5; wave wv step s handles i = (s*8+wv)*2+g.
// Agreement dot fully in-lane. b_ij is linear in history
// (b_t = <v_ic, sum_{tau<t} vj_tau>) -> only the cumulative vjr (16 regs)
// is carried; no per-i logit storage (avoids the round-3 register spill).
// unroll_count(2) caps load hoisting.
__global__ __launch_bounds__(512) void routing_k(const ushort* __restrict__ votes,
                                                 const float* __restrict__ afac,
                                                 float* __restrict__ out) {
    __shared__ float afs[NI];
    __shared__ float sred[8 * CQ];    // 16 KB
    __shared__ float vj[CQ];
    __shared__ float aout_s[NC];

    int n = blockIdx.x;
    int t = threadIdx.x;
    int wv = t >> 6;
    int l = t & 63;
    int c = l & 31;
    int g = l >> 5;

    for (int idx = t; idx < NI; idx += 512) afs[idx] = afac[n * NI + idx];
    __syncthreads();

    const ushort* vb = votes + (size_t)n * NI * CQ;
    float vjr[16];    // cumulative sum of vj over past iters
    float sreg[16];

    for (int iter = 0; iter < 3; ++iter) {
#pragma unroll
        for (int q = 0; q < 16; ++q) sreg[q] = 0.f;

        // depth-2 prefetch: rows for s and s+1
        const uint4* r0 = (const uint4*)(vb + ((size_t)((0 * 8 + wv) * 2 + g) << 9) + (c << 4));
        uint4 a0 = r0[0], a1 = r0[1];
        const uint4* r1 = (const uint4*)(vb + ((size_t)((1 * 8 + wv) * 2 + g) << 9) + (c << 4));
        uint4 b0 = r1[0], b1 = r1[1];

#pragma clang loop unroll_count(2)
        for (int s = 0; s < 18; ++s) {
            int i = ((s << 3) + wv) * 2 + g;
            uint4 c0 = a0, c1 = a1;
            a0 = b0; a1 = b1;
            if (s + 2 < 18) {
                const uint4* rn = (const uint4*)(vb + ((size_t)((((s + 2) << 3) + wv) * 2 + g) << 9) + (c << 4));
                b0 = rn[0]; b1 = rn[1];
            }
            float vt[16];
            {
                float2 f;
                f = __half22float2(*(const __half2*)&c0.x); vt[0] = f.x;  vt[1] = f.y;
                f = __half22float2(*(const __half2*)&c0.y); vt[2] = f.x;  vt[3] = f.y;
                f = __half22float2(*(const __half2*)&c0.z); vt[4] = f.x;  vt[5] = f.y;
                f = __half22float2(*(const __half2*)&c0.w); vt[6] = f.x;  vt[7] = f.y;
                f = __half22float2(*(const __half2*)&c1.x); vt[8] = f.x;  vt[9] = f.y;
                f = __half22float2(*(const __half2*)&c1.y); vt[10] = f.x; vt[11] = f.y;
                f = __half22float2(*(const __half2*)&c1.z); vt[12] = f.x; vt[13] = f.y;
                f = __half22float2(*(const __half2*)&c1.w); vt[14] = f.x; vt[15] = f.y;
            }
            float cij;
            if (iter == 0) {
                cij = afs[i] * (1.0f / 32.0f);
            } else {
                float ah = 0.f;
#pragma unroll
                for (int q = 0; q < 16; ++q) ah += vt[q] * vjr[q];
                float e = __expf(ah);   // |b| <= ~0.7: no max-sub needed
                float ssum = e;
                ssum += __shfl_xor(ssum, 1);
                ssum += __shfl_xor(ssum, 2);
                ssum += __shfl_xor(ssum, 4);
                ssum += __shfl_xor(ssum, 8);
                ssum += __shfl_xor(ssum, 16);
                cij = e * __builtin_amdgcn_rcpf(ssum) * afs[i];
            }
#pragma unroll
            for (int q = 0; q < 16; ++q) sreg[q] += cij * vt[q];
        }

        // fold the two g-halves in-wave, then write 8 partial groups [c][q]
#pragma unroll
        for (int q = 0; q < 16; ++q) sreg[q] += __shfl_xor(sreg[q], 32);
        if (g == 0) {
            float* sw = &sred[wv * CQ + (c << 4)];
#pragma unroll
            for (int q4 = 0; q4 < 4; ++q4)
                *(float4*)(sw + q4 * 4) = make_float4(sreg[q4 * 4], sreg[q4 * 4 + 1],
                                                      sreg[q4 * 4 + 2], sreg[q4 * 4 + 3]);
        }
        __syncthreads();
        {
            float ssum = 0.f;
#pragma unroll
            for (int k = 0; k < 8; ++k) ssum += sred[k * CQ + t];
            sred[t] = ssum;   // per-thread column: safe
        }
        __syncthreads();

        // squash (threads 0..31, one c each)
        if (t < NC) {
            float s2 = 0.f;
#pragma unroll
            for (int q = 0; q < 16; ++q) {
                float s = sred[t * 16 + q];
                s2 += s * s;
            }
            float f = (s2 / (1.f + s2)) / sqrtf(s2 + EPSV);
            float vn2 = 0.f;
#pragma unroll
            for (int q = 0; q < 16; ++q) {
                float v = f * sred[t * 16 + q];
                vj[t * 16 + q] = v;
                vn2 += v * v;
            }
            if (iter == 2) {
                float ao = sqrtf(vn2 + EPSV);
                ao = fminf(fmaxf(ao, 1e-4f), 1.f - 1e-4f);
                aout_s[t] = ao;
            }
        }
        __syncthreads();
        if (iter < 2) {
            const float4* vp4 = (const float4*)(&vj[c << 4]);
#pragma unroll
            for (int q4 = 0; q4 < 4; ++q4) {
                float4 f = vp4[q4];
                if (iter == 0) {
                    vjr[q4 * 4] = f.x; vjr[q4 * 4 + 1] = f.y;
                    vjr[q4 * 4 + 2] = f.z; vjr[q4 * 4 + 3] = f.w;
                } else {
                    vjr[q4 * 4] += f.x; vjr[q4 * 4 + 1] += f.y;
                    vjr[q4 * 4 + 2] += f.z; vjr[q4 * 4 + 3] += f.w;
                }
            }
        }
    }

    // outputs: p_out, a_out, concat(out)
    {
        float v = vj[t];   // 512 threads == CQ
        out[(size_t)n * CQ + t] = v;
        out[OFF_CAT + (size_t)n * 544 + t] = v;
    }
    if (t < NC) {
        float ao = aout_s[t];
        out[OFF_AOUT + n * 32 + t] = ao;
        out[OFF_CAT + (size_t)n * 544 + 512 + t] = ao;
    }
}

// ---------------------------------------------------------------------------
extern "C" void kernel_launch(void* const* d_in, const int* in_sizes, int n_in,
                              void* d_out, int out_size, void* d_ws, size_t ws_size,
                              hipStream_t stream) {
    const float* x = (const float*)d_in[0];
    const float* wts = (const float*)d_in[1];
    float* out = (float*)d_out;
    float* ws = (float*)d_ws;

    float* afac = ws + OFF_AFAC;
    ushort* p16 = (ushort*)(ws + OFF_P16);
    ushort* w16 = (ushort*)(ws + OFF_W16);
    ushort* votes = (ushort*)(ws + OFF_VOT);

    hipLaunchKernelGGL(prep_w, dim3(NI), dim3(256), 0, stream, wts, w16);
    hipLaunchKernelGGL(prep_pa, dim3((P16E + AFACE + 255) / 256), dim3(256), 0, stream,
                       x, p16, afac);
    hipLaunchKernelGGL(votes_k, dim3(7, NI), dim3(256), 0, stream,
                       p16, w16, votes);
    hipLaunchKernelGGL(routing_k, dim3(NB), dim3(512), 0, stream,
                       votes, afac, out);
}

// Round 7
// 151.290 us; speedup vs baseline: 1.8682x; 1.0546x over previous
//
#include <hip/hip_runtime.h>
#include <hip/hip_fp16.h>
#include <math.h>

// Problem constants
#define NB 392      // n = b*oh*ow = 2*14*14
#define NI 288      // K*K*B = 9*32
#define NC 32       // C
#define NQ 16       // PSIZE
#define CQ 512      // NC*NQ
#define CH 544      // B*(PSIZE+1)
#define EPSV 1e-6f
#define NPAD 448    // n padded to 7 tiles of 64 rows

// element counts
#define P16E (NI*NPAD*32)     // p16[i][n][32k]  fp16, k>=16 zero-pad
#define W16E (NI*CQ*32)       // w16[i][cq][32k] fp16, k>=16 zero-pad
#define AFACE (NB*NI)         // afac floats

// ws float offsets
#define OFF_AFAC 0
#define OFF_P16  (AFACE)
#define OFF_W16  (OFF_P16 + P16E/2)
#define OFF_VOT  (OFF_W16 + W16E/2)

// out layout (floats)
#define OFF_AOUT 200704       // NB*CQ
#define OFF_CAT  213248       // OFF_AOUT + NB*NC

typedef _Float16 v8h __attribute__((ext_vector_type(8)));
typedef float v4f __attribute__((ext_vector_type(4)));

// ---------------------------------------------------------------------------
// Gather from x via the unfold channel-major reinterpret.
__device__ __forceinline__ float gather_x(const float* __restrict__ x, int n, int j) {
    int c_idx = j / 9;
    int rem = j - c_idx * 9;
    int ki = rem / 3;
    int kj = rem - ki * 3;
    int b_ = n / 196;
    int rest = n - b_ * 196;
    int yy = rest / 14;
    int xx = rest - yy * 14;
    int iy = yy + ki - 1;
    int ix = xx + kj - 1;
    float v = 0.f;
    if ((unsigned)iy < 14u && (unsigned)ix < 14u)
        v = x[((b_ * 14 + iy) * 14 + ix) * CH + c_idx];
    return v;
}

// p16 (fp16, padded) + afac (fp32): grid-stride elementwise.
__global__ __launch_bounds__(256) void prep_pa(const float* __restrict__ x,
                                               ushort* __restrict__ p16,
                                               float* __restrict__ afac) {
    int tid = blockIdx.x * 256 + threadIdx.x;
    if (tid < P16E) {
        int k = tid & 31;
        int i = tid / (NPAD * 32);
        int n = (tid >> 5) - i * NPAD;
        float v = 0.f;
        if (n < NB && k < 16) {
            int j = (i >> 5) * CH + (i & 31) * 16 + k;
            v = gather_x(x, n, j);
        }
        p16[tid] = __half_as_ushort(__float2half(v));
    } else if (tid < P16E + AFACE) {
        int t3 = tid - P16E;
        int i = t3 % NI;
        int n = t3 / NI;
        int j = (i >> 5) * CH + 512 + (i & 31);
        float v = gather_x(x, n, j);
        float a = fminf(fmaxf(v, 1e-4f), 1.0f);
        afac[t3] = a / (a + EPSV);
    }
}

// w16[i][cq][32k] = wts[i][cq>>4][k][cq&15] (k<16), via LDS transpose.
// Block per i: coalesced float4 reads, coalesced uint (half2) writes.
__global__ __launch_bounds__(256) void prep_w(const float* __restrict__ wts,
                                              ushort* __restrict__ w16) {
    __shared__ float wl[8192];   // 32 KB: wts[i] tile, [c][p][q] flat
    int i = blockIdx.x;
    int t = threadIdx.x;
    const float4* src = (const float4*)(wts + (size_t)i * 8192);
#pragma unroll
    for (int it = 0; it < 8; ++it)
        *(float4*)&wl[(it * 256 + t) * 4] = src[it * 256 + t];
    __syncthreads();
    uint* dst = (uint*)(w16 + (size_t)i * 16384);
    for (int it = 0; it < 32; ++it) {
        int idx = it * 256 + t;          // uint index = cq*16 + kpair
        int kpair = idx & 15;
        int cq = idx >> 4;
        uint val = 0;
        if (kpair < 8) {
            int base = (cq >> 4) * 256 + (cq & 15);
            __half2 h = __floats2half2_rn(wl[base + (2 * kpair) * 16],
                                          wl[base + (2 * kpair + 1) * 16]);
            val = *(uint*)&h;
        }
        dst[idx] = val;
    }
}

// ---------------------------------------------------------------------------
// votes via MFMA, M=64 blocking, ct-CHUNKED staging. Block (mtt 0..6, i),
// 256 threads = 4 waves; wave wv owns rows [mtt*64+wv*16, +16).
// Per chunk: 8 ct-tiles -> LDS [64][136] halves (17 KB, 16B row pad), then
// 64 rows x 256 B contiguous stores (full 64B sectors, no amplification).
// 17 KB LDS keeps occupancy at the 8-block/CU wave cap (vs 2 with a 65 KB
// full tile) -- the round-6 version was latency-bound on 2 blocks/CU.
__global__ __launch_bounds__(256) void votes_k(const ushort* __restrict__ p16,
                                               const ushort* __restrict__ w16,
                                               ushort* __restrict__ votes) {
    __shared__ ushort tile[64 * 136];   // 17 KB
    int mtt = blockIdx.x;         // 0..6
    int i = blockIdx.y;           // 0..287
    int t = threadIdx.x;
    int wv = t >> 6;
    int l = t & 63;
    int col = l & 15;
    int quad = l >> 4;

    int row_a = mtt * 64 + wv * 16 + col;
    v8h av = *(const v8h*)(p16 + ((size_t)(i * NPAD + row_a) << 5) + (quad << 3));

    for (int ch = 0; ch < 4; ++ch) {
#pragma unroll
        for (int c8 = 0; c8 < 8; ++c8) {
            int ct = ch * 8 + c8;
            v8h bv = *(const v8h*)(w16 + ((size_t)(i * CQ + ct * 16 + col) << 5) + (quad << 3));
            v4f acc = {0.f, 0.f, 0.f, 0.f};
            acc = __builtin_amdgcn_mfma_f32_16x16x32_f16(av, bv, acc, 0, 0, 0);
#pragma unroll
            for (int r = 0; r < 4; ++r)
                tile[(wv * 16 + quad * 4 + r) * 136 + c8 * 16 + col] =
                    __half_as_ushort(__float2half(acc[r]));
        }
        __syncthreads();
        // 64 rows x 16 uint4 = 1024 uint4; 256 threads -> 4 steps.
        // 16 consecutive lanes store one row's 256 B chunk (4 full sectors).
#pragma unroll
        for (int k = 0; k < 4; ++k) {
            int idx = k * 256 + t;
            int row = idx >> 4;
            int off = idx & 15;
            int n_out = mtt * 64 + row;
            if (n_out < NB) {
                uint4 d = *(const uint4*)&tile[row * 136 + off * 8];
                *(uint4*)(votes + (((size_t)n_out * NI + i) << 9) + ch * 128 + off * 8) = d;
            }
        }
        __syncthreads();
    }
}

// ---------------------------------------------------------------------------
// Fused dynamic routing, 3 passes. Block = n, 512 threads (8 waves).
// Lane: c = l&31, g = l>>5; wave wv step s handles i = (s*8+wv)*2+g.
// Agreement dot fully in-lane. b_ij is linear in history
// (b_t = <v_ic, sum_{tau<t} vj_tau>) -> only the cumulative vjr (16 regs)
// is carried; no per-i logit storage (avoids the round-3 register spill).
// unroll_count(2) caps load hoisting.
__global__ __launch_bounds__(512) void routing_k(const ushort* __restrict__ votes,
                                                 const float* __restrict__ afac,
                                                 float* __restrict__ out) {
    __shared__ float afs[NI];
    __shared__ float sred[8 * CQ];    // 16 KB
    __shared__ float vj[CQ];
    __shared__ float aout_s[NC];

    int n = blockIdx.x;
    int t = threadIdx.x;
    int wv = t >> 6;
    int l = t & 63;
    int c = l & 31;
    int g = l >> 5;

    for (int idx = t; idx < NI; idx += 512) afs[idx] = afac[n * NI + idx];
    __syncthreads();

    const ushort* vb = votes + (size_t)n * NI * CQ;
    float vjr[16];    // cumulative sum of vj over past iters
    float sreg[16];

    for (int iter = 0; iter < 3; ++iter) {
#pragma unroll
        for (int q = 0; q < 16; ++q) sreg[q] = 0.f;

        // depth-2 prefetch: rows for s and s+1
        const uint4* r0 = (const uint4*)(vb + ((size_t)((0 * 8 + wv) * 2 + g) << 9) + (c << 4));
        uint4 a0 = r0[0], a1 = r0[1];
        const uint4* r1 = (const uint4*)(vb + ((size_t)((1 * 8 + wv) * 2 + g) << 9) + (c << 4));
        uint4 b0 = r1[0], b1 = r1[1];

#pragma clang loop unroll_count(2)
        for (int s = 0; s < 18; ++s) {
            int i = ((s << 3) + wv) * 2 + g;
            uint4 c0 = a0, c1 = a1;
            a0 = b0; a1 = b1;
            if (s + 2 < 18) {
                const uint4* rn = (const uint4*)(vb + ((size_t)((((s + 2) << 3) + wv) * 2 + g) << 9) + (c << 4));
                b0 = rn[0]; b1 = rn[1];
            }
            float vt[16];
            {
                float2 f;
                f = __half22float2(*(const __half2*)&c0.x); vt[0] = f.x;  vt[1] = f.y;
                f = __half22float2(*(const __half2*)&c0.y); vt[2] = f.x;  vt[3] = f.y;
                f = __half22float2(*(const __half2*)&c0.z); vt[4] = f.x;  vt[5] = f.y;
                f = __half22float2(*(const __half2*)&c0.w); vt[6] = f.x;  vt[7] = f.y;
                f = __half22float2(*(const __half2*)&c1.x); vt[8] = f.x;  vt[9] = f.y;
                f = __half22float2(*(const __half2*)&c1.y); vt[10] = f.x; vt[11] = f.y;
                f = __half22float2(*(const __half2*)&c1.z); vt[12] = f.x; vt[13] = f.y;
                f = __half22float2(*(const __half2*)&c1.w); vt[14] = f.x; vt[15] = f.y;
            }
            float cij;
            if (iter == 0) {
                cij = afs[i] * (1.0f / 32.0f);
            } else {
                float ah = 0.f;
#pragma unroll
                for (int q = 0; q < 16; ++q) ah += vt[q] * vjr[q];
                float e = __expf(ah);   // |b| <= ~0.7: no max-sub needed
                float ssum = e;
                ssum += __shfl_xor(ssum, 1);
                ssum += __shfl_xor(ssum, 2);
                ssum += __shfl_xor(ssum, 4);
                ssum += __shfl_xor(ssum, 8);
                ssum += __shfl_xor(ssum, 16);
                cij = e * __builtin_amdgcn_rcpf(ssum) * afs[i];
            }
#pragma unroll
            for (int q = 0; q < 16; ++q) sreg[q] += cij * vt[q];
        }

        // fold the two g-halves in-wave, then write 8 partial groups [c][q]
#pragma unroll
        for (int q = 0; q < 16; ++q) sreg[q] += __shfl_xor(sreg[q], 32);
        if (g == 0) {
            float* sw = &sred[wv * CQ + (c << 4)];
#pragma unroll
            for (int q4 = 0; q4 < 4; ++q4)
                *(float4*)(sw + q4 * 4) = make_float4(sreg[q4 * 4], sreg[q4 * 4 + 1],
                                                      sreg[q4 * 4 + 2], sreg[q4 * 4 + 3]);
        }
        __syncthreads();
        {
            float ssum = 0.f;
#pragma unroll
            for (int k = 0; k < 8; ++k) ssum += sred[k * CQ + t];
            sred[t] = ssum;   // per-thread column: safe
        }
        __syncthreads();

        // squash (threads 0..31, one c each)
        if (t < NC) {
            float s2 = 0.f;
#pragma unroll
            for (int q = 0; q < 16; ++q) {
                float s = sred[t * 16 + q];
                s2 += s * s;
            }
            float f = (s2 / (1.f + s2)) / sqrtf(s2 + EPSV);
            float vn2 = 0.f;
#pragma unroll
            for (int q = 0; q < 16; ++q) {
                float v = f * sred[t * 16 + q];
                vj[t * 16 + q] = v;
                vn2 += v * v;
            }
            if (iter == 2) {
                float ao = sqrtf(vn2 + EPSV);
                ao = fminf(fmaxf(ao, 1e-4f), 1.f - 1e-4f);
                aout_s[t] = ao;
            }
        }
        __syncthreads();
        if (iter < 2) {
            const float4* vp4 = (const float4*)(&vj[c << 4]);
#pragma unroll
            for (int q4 = 0; q4 < 4; ++q4) {
                float4 f = vp4[q4];
                if (iter == 0) {
                    vjr[q4 * 4] = f.x; vjr[q4 * 4 + 1] = f.y;
                    vjr[q4 * 4 + 2] = f.z; vjr[q4 * 4 + 3] = f.w;
                } else {
                    vjr[q4 * 4] += f.x; vjr[q4 * 4 + 1] += f.y;
                    vjr[q4 * 4 + 2] += f.z; vjr[q4 * 4 + 3] += f.w;
                }
            }
        }
    }

    // outputs: p_out, a_out, concat(out)
    {
        float v = vj[t];   // 512 threads == CQ
        out[(size_t)n * CQ + t] = v;
        out[OFF_CAT + (size_t)n * 544 + t] = v;
    }
    if (t < NC) {
        float ao = aout_s[t];
        out[OFF_AOUT + n * 32 + t] = ao;
        out[OFF_CAT + (size_t)n * 544 + 512 + t] = ao;
    }
}

// ---------------------------------------------------------------------------
extern "C" void kernel_launch(void* const* d_in, const int* in_sizes, int n_in,
                              void* d_out, int out_size, void* d_ws, size_t ws_size,
                              hipStream_t stream) {
    const float* x = (const float*)d_in[0];
    const float* wts = (const float*)d_in[1];
    float* out = (float*)d_out;
    float* ws = (float*)d_ws;

    float* afac = ws + OFF_AFAC;
    ushort* p16 = (ushort*)(ws + OFF_P16);
    ushort* w16 = (ushort*)(ws + OFF_W16);
    ushort* votes = (ushort*)(ws + OFF_VOT);

    hipLaunchKernelGGL(prep_w, dim3(NI), dim3(256), 0, stream, wts, w16);
    hipLaunchKernelGGL(prep_pa, dim3((P16E + AFACE + 255) / 256), dim3(256), 0, stream,
                       x, p16, afac);
    hipLaunchKernelGGL(votes_k, dim3(7, NI), dim3(256), 0, stream,
                       p16, w16, votes);
    hipLaunchKernelGGL(routing_k, dim3(NB), dim3(512), 0, stream,
                       votes, afac, out);
}